// Round 10
// baseline (117.428 us; speedup 1.0000x reference)
//
#include <hip/hip_runtime.h>
#include <math.h>

typedef __attribute__((ext_vector_type(4))) float f32x4;
typedef __attribute__((ext_vector_type(16))) float f32x16;
typedef _Float16 f16x8 __attribute__((ext_vector_type(8)));
typedef __fp16 fp16x2 __attribute__((ext_vector_type(2)));

#define MFMA16(a, b, c) __builtin_amdgcn_mfma_f32_16x16x32_f16((a), (b), (c), 0, 0, 0)
#define MFMA32(a, b, c) __builtin_amdgcn_mfma_f32_32x32x16_f16((a), (b), (c), 0, 0, 0)

__device__ __forceinline__ unsigned short f2h(float f) {
    union { _Float16 h; unsigned short u; } v; v.h = (_Float16)f; return v.u;
}
__device__ __forceinline__ unsigned pk2f(float a, float b) {
    union { fp16x2 h; unsigned u; } v; v.h = __builtin_amdgcn_cvt_pkrtz(a, b); return v.u;
}

#if defined(__has_builtin)
#if __has_builtin(__builtin_amdgcn_global_load_lds)
#define HAVE_GLL 1
#endif
#endif

__device__ __forceinline__ void gload16(const void* g, void* lds) {
#ifdef HAVE_GLL
    __builtin_amdgcn_global_load_lds(
        (const __attribute__((address_space(1))) void*)g,
        (__attribute__((address_space(3))) void*)lds, 16, 0, 0);
#else
    *(f16x8*)lds = *(const f16x8*)g;
#endif
}

// ---------------------------------------------------------------- prep X (f32 -> f16)
__global__ __launch_bounds__(256) void prep_x_kernel(
    const float* __restrict__ X, unsigned short* __restrict__ XF) {
    int i = (blockIdx.x * 256 + threadIdx.x) * 4;
    float4 v = *reinterpret_cast<const float4*>(X + i);
    ushort4 h;
    h.x = f2h(v.x); h.y = f2h(v.y); h.z = f2h(v.z); h.w = f2h(v.w);
    *reinterpret_cast<ushort4*>(XF + i) = h;
}

// ---------------------------------------------------------------- prep W (transpose + f16)
__global__ __launch_bounds__(256) void prep_w_kernel(
    const float* __restrict__ Wq, const float* __restrict__ Wk,
    const float* __restrict__ Wv, unsigned short* __restrict__ WT) {
    __shared__ float T[64][65];
    int z = blockIdx.z;
    const float* W = (z == 0) ? Wq : ((z == 1) ? Wk : Wv);
    unsigned short* Wo = WT + (size_t)z * 1024 * 1024;
    int k0 = blockIdx.x * 64, n0 = blockIdx.y * 64;
    int t = threadIdx.x;
    for (int i = 0; i < 4; i++) {
        int fid = t + i * 256;
        int rr = fid >> 4, cc = fid & 15;
        float4 v = *reinterpret_cast<const float4*>(W + (size_t)(k0 + rr) * 1024 + n0 + cc * 4);
        T[rr][cc * 4 + 0] = v.x; T[rr][cc * 4 + 1] = v.y;
        T[rr][cc * 4 + 2] = v.z; T[rr][cc * 4 + 3] = v.w;
    }
    __syncthreads();
    for (int i = 0; i < 4; i++) {
        int e = t + i * 256;
        int n = e >> 4, kq = (e & 15) * 4;
        ushort4 h;
        h.x = f2h(T[kq + 0][n]); h.y = f2h(T[kq + 1][n]);
        h.z = f2h(T[kq + 2][n]); h.w = f2h(T[kq + 3][n]);
        size_t o = (size_t)(n0 + n) * 1024 + k0 + kq;
        *reinterpret_cast<ushort4*>(Wo + o) = h;
    }
}

// ---------------------------------------------------------------- QKV GEMM (f16, counted-vmcnt pipeline)
// 128x128 tile, BK=32, 3-deep LDS (48KB -> 3 blocks/CU), 4 waves x (64x64).
__global__ __launch_bounds__(256, 3) void qkv_gemm_kernel(
    const unsigned short* __restrict__ XF, const unsigned short* __restrict__ WT,
    const float* __restrict__ bq, const float* __restrict__ bk,
    const float* __restrict__ bv,
    unsigned short* __restrict__ QF, unsigned short* __restrict__ KF,
    unsigned short* __restrict__ VT) {
    __shared__ __align__(16) char smem[3][2][8192];  // [buf][X,W][128 rows x 64B]
    int z = blockIdx.z;
    const unsigned short* Wz = WT + (size_t)z * 1024 * 1024;
    const float* bias = (z == 0) ? bq : ((z == 1) ? bk : bv);
    const int m0 = blockIdx.x * 128, n0 = blockIdx.y * 128;
    const int tid = threadIdx.x, lane = tid & 63, wid = tid >> 6;
    const int wr = wid >> 1, wc = wid & 1;
    const int g = lane >> 4, r16 = lane & 15;

    f32x4 acc[4][4] = {};

#define QSTAGE(BUFI, K0)                                                             \
    {                                                                                \
        _Pragma("unroll")                                                            \
        for (int p = 0; p < 2; ++p) {                                                \
            int row = p * 64 + (tid >> 2);                                           \
            int ec = ((tid & 3) ^ (row & 3)) * 8;                                    \
            size_t xo = (size_t)(m0 + row) * 1024 + (K0) + ec;                       \
            size_t wo = (size_t)(n0 + row) * 1024 + (K0) + ec;                       \
            gload16(XF + xo, &smem[(BUFI)][0][0] + p * 4096 + tid * 16);             \
            gload16(Wz + wo, &smem[(BUFI)][1][0] + p * 4096 + tid * 16);             \
        }                                                                            \
    }

    QSTAGE(0, 0);
    QSTAGE(1, 32);
    int bufc = 0, bufs = 2;
    for (int ki = 0; ki < 32; ++ki) {
        if (ki < 31) {
            asm volatile("s_waitcnt vmcnt(4)" ::: "memory");
        } else {
            asm volatile("s_waitcnt vmcnt(0)" ::: "memory");
        }
        __builtin_amdgcn_s_barrier();
        if (ki < 30) QSTAGE(bufs, (ki + 2) * 32);
        const char* bX = &smem[bufc][0][0];
        const char* bW = &smem[bufc][1][0];
        const int sx = (r16 & 3) << 4;

        f16x8 af[4], bf[4];
#pragma unroll
        for (int mi = 0; mi < 4; ++mi)
            af[mi] = *(const f16x8*)(bX + (wr * 64 + mi * 16 + r16) * 64 + ((g << 4) ^ sx));
#pragma unroll
        for (int ni = 0; ni < 4; ++ni)
            bf[ni] = *(const f16x8*)(bW + (wc * 64 + ni * 16 + r16) * 64 + ((g << 4) ^ sx));
        __builtin_amdgcn_s_setprio(1);
#pragma unroll
        for (int mi = 0; mi < 4; ++mi)
#pragma unroll
            for (int ni = 0; ni < 4; ++ni)
                acc[mi][ni] = MFMA16(af[mi], bf[ni], acc[mi][ni]);
        __builtin_amdgcn_s_setprio(0);
        bufc = (bufc == 2) ? 0 : bufc + 1;
        bufs = (bufs == 2) ? 0 : bufs + 1;
    }

    // epilogue: frag D row = g*4+r (m), col = r16 (n)
#pragma unroll
    for (int mi = 0; mi < 4; ++mi)
#pragma unroll
        for (int ni = 0; ni < 4; ++ni)
#pragma unroll
            for (int r = 0; r < 4; ++r) {
                int m = m0 + wr * 64 + mi * 16 + g * 4 + r;
                int n = n0 + wc * 64 + ni * 16 + r16;
                float val = acc[mi][ni][r] + bias[n];
                if (z == 0) val *= 0.18033688011112042f;  // 0.125 * log2(e)
                int b = m >> 11, s = m & 2047, hh = n >> 6, d = n & 63;
                unsigned short hv = f2h(val);
                if (z == 2) {
                    VT[((size_t)(b * 16 + hh) * 64 + d) * 2048 + s] = hv;
                } else {
                    size_t o = ((size_t)(b * 16 + hh) * 2048 + s) * 64 + d;
                    if (z == 0) QF[o] = hv; else KF[o] = hv;
                }
            }
}

// ---------------------------------------------------------------- attention (flash, 32x32 MFMA, f16)
// grid (8, 32); block 512 = 8 waves x 32 q-rows (QBLK 256, 1 block/CU -> 2x K/V reuse).
// KVBLK=64, 4-deep LDS, one barrier/chunk, vmcnt(2) ledger (2 loads/stage/wave),
// QK^T one chunk ahead (scA/scB), shfl_xor P-pack (r8-proven).
__global__ __launch_bounds__(512, 2) void attn_kernel(
    const unsigned short* __restrict__ QF, const unsigned short* __restrict__ KF,
    const unsigned short* __restrict__ VT, const int* __restrict__ mask,
    float* __restrict__ out) {
    __shared__ __align__(16) char smem[4][2][8192];  // [buf][K,V][64 rows x 128B]
    __shared__ __align__(16) float cmlds[2048];
    const int tid = threadIdx.x;
    const int lane = tid & 63, wid = tid >> 6;
    const int hi = lane >> 5, l31 = lane & 31;
    const int bh = blockIdx.y, b = bh >> 4, h = bh & 15;
    const size_t base = (size_t)bh * 2048 * 64;
    const unsigned short* KFh = KF + base;
    const unsigned short* VTh = VT + base;
    const int qrow = blockIdx.x * 256 + wid * 32 + l31;
    const int swz = (l31 & 7) << 4;

    // Q fragments (B operand): lane holds q = l31, k-elems = ks*16 + hi*8 .. +7
    f16x8 qf[4];
#pragma unroll
    for (int ks = 0; ks < 4; ++ks)
        qf[ks] = *reinterpret_cast<const f16x8*>(QF + base + (size_t)qrow * 64 + ks * 16 + hi * 8);

    // staging: waves 0-3 -> K plane, 4-7 -> V plane; each wave 16 rows (2 loads).
    const int lr = lane >> 3, c16 = lane & 7;
    const int gce = (c16 ^ lr) << 3;
    const int pl8 = wid >> 2, w4 = wid & 3;
    const unsigned short* mys = pl8 ? VTh : KFh;
    const int rstr = pl8 ? 2048 : 64;

    f32x16 ctx[2] = {};
    float l_st = 0.f;

#define STAGE(BUFI, K0)                                                              \
    {                                                                                \
        char* dst = &smem[(BUFI)][pl8][0] + w4 * 2048;                               \
        size_t koff = pl8 ? (size_t)(K0) : (size_t)(K0) * 64;                        \
        _Pragma("unroll")                                                            \
        for (int i = 0; i < 2; ++i) {                                                \
            int r = w4 * 16 + i * 8 + lr;                                            \
            gload16(mys + koff + (size_t)r * rstr + gce, dst + i * 1024 + lane * 16);\
        }                                                                            \
    }

#define QKT(CH, SC)                                                                  \
    {                                                                                \
        const char* bK = &smem[(CH) & 3][0][0];                                      \
        __builtin_amdgcn_s_setprio(1);                                               \
        _Pragma("unroll")                                                            \
        for (int kt = 0; kt < 2; ++kt) {                                             \
            const char* rK = bK + (kt * 32 + l31) * 128;                             \
            f32x16 a = {};                                                           \
            _Pragma("unroll")                                                        \
            for (int ks = 0; ks < 4; ++ks)                                           \
                a = MFMA32(*(const f16x8*)(rK + ((ks * 32 + hi * 16) ^ swz)),        \
                           qf[ks], a);                                               \
            SC[kt] = a;                                                              \
        }                                                                            \
        __builtin_amdgcn_s_setprio(0);                                               \
    }

#define SMPV(CH, SC)                                                                 \
    {                                                                                \
        const int k0s = (CH) * 64;                                                   \
        const char* bV = &smem[(CH) & 3][1][0];                                      \
        float p[32];                                                                 \
        _Pragma("unroll")                                                            \
        for (int kt = 0; kt < 2; ++kt)                                               \
            _Pragma("unroll")                                                        \
            for (int r = 0; r < 16; ++r) p[kt * 16 + r] = SC[kt][r];                 \
        float psum = 0.f;                                                            \
        _Pragma("unroll")                                                            \
        for (int kt = 0; kt < 2; ++kt)                                               \
            _Pragma("unroll")                                                        \
            for (int G = 0; G < 4; ++G) {                                            \
                float4 cv = *reinterpret_cast<const float4*>(                        \
                    &cmlds[k0s + kt * 32 + 8 * G + 4 * hi]);                         \
                int bo = kt * 16 + G * 4;                                            \
                float e0 = __builtin_amdgcn_exp2f(p[bo + 0] + cv.x);                 \
                float e1 = __builtin_amdgcn_exp2f(p[bo + 1] + cv.y);                 \
                float e2 = __builtin_amdgcn_exp2f(p[bo + 2] + cv.z);                 \
                float e3 = __builtin_amdgcn_exp2f(p[bo + 3] + cv.w);                 \
                p[bo + 0] = e0; p[bo + 1] = e1; p[bo + 2] = e2; p[bo + 3] = e3;      \
                psum += e0 + e1 + e2 + e3;                                           \
            }                                                                        \
        l_st += psum;                                                                \
        f16x8 pf[4];                                                                 \
        _Pragma("unroll")                                                            \
        for (int kt = 0; kt < 2; ++kt) {                                             \
            int bo = kt * 16;                                                        \
            unsigned a0 = pk2f(p[bo + 0], p[bo + 1]),   a1 = pk2f(p[bo + 2], p[bo + 3]);   \
            unsigned b0 = pk2f(p[bo + 4], p[bo + 5]),   b1 = pk2f(p[bo + 6], p[bo + 7]);   \
            unsigned c0 = pk2f(p[bo + 8], p[bo + 9]),   c1 = pk2f(p[bo + 10], p[bo + 11]); \
            unsigned d0 = pk2f(p[bo + 12], p[bo + 13]), d1 = pk2f(p[bo + 14], p[bo + 15]); \
            unsigned ta0 = __shfl_xor((int)a0, 32), ta1 = __shfl_xor((int)a1, 32);   \
            unsigned tb0 = __shfl_xor((int)b0, 32), tb1 = __shfl_xor((int)b1, 32);   \
            unsigned tc0 = __shfl_xor((int)c0, 32), tc1 = __shfl_xor((int)c1, 32);   \
            unsigned td0 = __shfl_xor((int)d0, 32), td1 = __shfl_xor((int)d1, 32);   \
            union { unsigned u[4]; f16x8 v; } f0, f1;                                \
            f0.u[0] = hi ? tb0 : a0; f0.u[1] = hi ? tb1 : a1;                        \
            f0.u[2] = hi ? b0 : ta0; f0.u[3] = hi ? b1 : ta1;                        \
            f1.u[0] = hi ? td0 : c0; f1.u[1] = hi ? td1 : c1;                        \
            f1.u[2] = hi ? d0 : tc0; f1.u[3] = hi ? d1 : tc1;                        \
            pf[kt * 2 + 0] = f0.v; pf[kt * 2 + 1] = f1.v;                            \
        }                                                                            \
        __builtin_amdgcn_s_setprio(1);                                               \
        _Pragma("unroll")                                                            \
        for (int dt = 0; dt < 2; ++dt) {                                             \
            const char* rV = bV + (dt * 32 + l31) * 128;                             \
            f32x16 a = ctx[dt];                                                      \
            _Pragma("unroll")                                                        \
            for (int ks = 0; ks < 4; ++ks)                                           \
                a = MFMA32(*(const f16x8*)(rV + ((ks * 32 + hi * 16) ^ swz)),        \
                           pf[ks], a);                                               \
            ctx[dt] = a;                                                             \
        }                                                                            \
        __builtin_amdgcn_s_setprio(0);                                               \
    }

#define WAIT2 asm volatile("s_waitcnt vmcnt(2)" ::: "memory")
#define WAIT0 asm volatile("s_waitcnt vmcnt(0)" ::: "memory")
#define BAR __builtin_amdgcn_s_barrier()

    STAGE(0, 0);
    STAGE(1, 64);
    STAGE(2, 128);
    // cmask -> LDS (c = mask ? -13 : -1e9), overlaps staging flight
    {
        const int* mrow = mask + b * 2048;
        int4 mv = *reinterpret_cast<const int4*>(mrow + tid * 4);
        float4 c0;
        c0.x = mv.x ? -13.f : -1e9f; c0.y = mv.y ? -13.f : -1e9f;
        c0.z = mv.z ? -13.f : -1e9f; c0.w = mv.w ? -13.f : -1e9f;
        *reinterpret_cast<float4*>(&cmlds[tid * 4]) = c0;
    }
    asm volatile("s_waitcnt vmcnt(4) lgkmcnt(0)" ::: "memory");
    BAR;

    f32x16 scA[2], scB[2];
    QKT(0, scA);
    for (int ch = 0; ch < 28; ch += 2) {
        WAIT2; BAR;
        STAGE((ch + 3) & 3, (ch + 3) * 64);
        QKT(ch + 1, scB);
        SMPV(ch, scA);
        WAIT2; BAR;
        STAGE((ch + 4) & 3, (ch + 4) * 64);
        QKT(ch + 2, scA);
        SMPV(ch + 1, scB);
    }
    // ch = 28
    WAIT2; BAR;
    STAGE(3, 31 * 64);
    QKT(29, scB);
    SMPV(28, scA);
    // ch = 29
    WAIT2; BAR;
    QKT(30, scA);
    SMPV(29, scB);
    // ch = 30
    WAIT0; BAR;
    QKT(31, scB);
    SMPV(30, scA);
    // ch = 31
    SMPV(31, scB);

    // ---- epilogue: lane q = l31; d = dt*32 + 8*G + 4*hi + j
    float l_full = l_st + __shfl_xor(l_st, 32);
    float inv_l = 1.0f / l_full;
    size_t ob0 = ((size_t)b * 2048 + qrow) * 1024 + h * 64 + 4 * hi;
#pragma unroll
    for (int dt = 0; dt < 2; ++dt)
#pragma unroll
        for (int G = 0; G < 4; ++G) {
            float4 st;
            st.x = ctx[dt][G * 4 + 0] * inv_l;
            st.y = ctx[dt][G * 4 + 1] * inv_l;
            st.z = ctx[dt][G * 4 + 2] * inv_l;
            st.w = ctx[dt][G * 4 + 3] * inv_l;
            *reinterpret_cast<float4*>(out + ob0 + dt * 32 + 8 * G) = st;
        }
}

// ---------------------------------------------------------------- launch
extern "C" void kernel_launch(void* const* d_in, const int* in_sizes, int n_in,
                              void* d_out, int out_size, void* d_ws, size_t ws_size,
                              hipStream_t stream) {
    const float* X  = (const float*)d_in[0];
    const int* mask = (const int*)d_in[1];
    const float* Wq = (const float*)d_in[2];
    const float* bq = (const float*)d_in[3];
    const float* Wk = (const float*)d_in[4];
    const float* bk = (const float*)d_in[5];
    const float* Wv = (const float*)d_in[6];
    const float* bv = (const float*)d_in[7];
    float* out = (float*)d_out;

    char* ws = (char*)d_ws;
    const size_t SZ_X = (size_t)4096 * 1024 * 2;        // 8 MB f16 X
    const size_t SZ_W = (size_t)1024 * 1024 * 2;        // 2 MB per W plane
    const size_t SZ_Q = (size_t)2 * 16 * 2048 * 64 * 2; // 8 MB per QKV plane
    unsigned short* XF = (unsigned short*)(ws);
    unsigned short* WT = (unsigned short*)(ws + SZ_X);
    unsigned short* QF = (unsigned short*)(ws + SZ_X + 3 * SZ_W);
    unsigned short* KF = (unsigned short*)(ws + SZ_X + 3 * SZ_W + 1 * SZ_Q);
    unsigned short* VT = (unsigned short*)(ws + SZ_X + 3 * SZ_W + 2 * SZ_Q);

    prep_x_kernel<<<4096, 256, 0, stream>>>(X, XF);
    prep_w_kernel<<<dim3(16, 16, 3), 256, 0, stream>>>(Wq, Wk, Wv, WT);
    qkv_gemm_kernel<<<dim3(32, 8, 3), 256, 0, stream>>>(XF, WT, bq, bk, bv, QF, KF, VT);
    attn_kernel<<<dim3(8, 32), 512, 0, stream>>>(QF, KF, VT, mask, out);
}

// Round 11
// 115.665 us; speedup vs baseline: 1.0152x; 1.0152x over previous
//
#include <hip/hip_runtime.h>
#include <math.h>

typedef __attribute__((ext_vector_type(4))) float f32x4;
typedef __attribute__((ext_vector_type(16))) float f32x16;
typedef _Float16 f16x8 __attribute__((ext_vector_type(8)));
typedef __fp16 fp16x2 __attribute__((ext_vector_type(2)));

#define MFMA16(a, b, c) __builtin_amdgcn_mfma_f32_16x16x32_f16((a), (b), (c), 0, 0, 0)
#define MFMA32(a, b, c) __builtin_amdgcn_mfma_f32_32x32x16_f16((a), (b), (c), 0, 0, 0)

__device__ __forceinline__ unsigned short f2h(float f) {
    union { _Float16 h; unsigned short u; } v; v.h = (_Float16)f; return v.u;
}
__device__ __forceinline__ float h2f(unsigned short u) {
    union { unsigned short u; _Float16 h; } v; v.u = u; return (float)v.h;
}
__device__ __forceinline__ unsigned pk2f(float a, float b) {
    union { fp16x2 h; unsigned u; } v; v.h = __builtin_amdgcn_cvt_pkrtz(a, b); return v.u;
}

#if defined(__has_builtin)
#if __has_builtin(__builtin_amdgcn_global_load_lds)
#define HAVE_GLL 1
#endif
#endif

__device__ __forceinline__ void gload16(const void* g, void* lds) {
#ifdef HAVE_GLL
    __builtin_amdgcn_global_load_lds(
        (const __attribute__((address_space(1))) void*)g,
        (__attribute__((address_space(3))) void*)lds, 16, 0, 0);
#else
    *(f16x8*)lds = *(const f16x8*)g;
#endif
}

// ---------------------------------------------------------------- prep X (f32 -> f16)
__global__ __launch_bounds__(256) void prep_x_kernel(
    const float* __restrict__ X, unsigned short* __restrict__ XF) {
    int i = (blockIdx.x * 256 + threadIdx.x) * 4;
    float4 v = *reinterpret_cast<const float4*>(X + i);
    ushort4 h;
    h.x = f2h(v.x); h.y = f2h(v.y); h.z = f2h(v.z); h.w = f2h(v.w);
    *reinterpret_cast<ushort4*>(XF + i) = h;
}

// ---------------------------------------------------------------- prep W (transpose + f16)
__global__ __launch_bounds__(256) void prep_w_kernel(
    const float* __restrict__ Wq, const float* __restrict__ Wk,
    const float* __restrict__ Wv, unsigned short* __restrict__ WT) {
    __shared__ float T[64][65];
    int z = blockIdx.z;
    const float* W = (z == 0) ? Wq : ((z == 1) ? Wk : Wv);
    unsigned short* Wo = WT + (size_t)z * 1024 * 1024;
    int k0 = blockIdx.x * 64, n0 = blockIdx.y * 64;
    int t = threadIdx.x;
    for (int i = 0; i < 4; i++) {
        int fid = t + i * 256;
        int rr = fid >> 4, cc = fid & 15;
        float4 v = *reinterpret_cast<const float4*>(W + (size_t)(k0 + rr) * 1024 + n0 + cc * 4);
        T[rr][cc * 4 + 0] = v.x; T[rr][cc * 4 + 1] = v.y;
        T[rr][cc * 4 + 2] = v.z; T[rr][cc * 4 + 3] = v.w;
    }
    __syncthreads();
    for (int i = 0; i < 4; i++) {
        int e = t + i * 256;
        int n = e >> 4, kq = (e & 15) * 4;
        ushort4 h;
        h.x = f2h(T[kq + 0][n]); h.y = f2h(T[kq + 1][n]);
        h.z = f2h(T[kq + 2][n]); h.w = f2h(T[kq + 3][n]);
        size_t o = (size_t)(n0 + n) * 1024 + k0 + kq;
        *reinterpret_cast<ushort4*>(Wo + o) = h;
    }
}

// ---------------------------------------------------------------- QKV GEMM (f16, counted-vmcnt pipeline)
// 128x128 tile, BK=32, 3-deep LDS (48KB -> 3 blocks/CU), 4 waves x (64x64).
__global__ __launch_bounds__(256, 3) void qkv_gemm_kernel(
    const unsigned short* __restrict__ XF, const unsigned short* __restrict__ WT,
    const float* __restrict__ bq, const float* __restrict__ bk,
    const float* __restrict__ bv,
    unsigned short* __restrict__ QF, unsigned short* __restrict__ KF,
    unsigned short* __restrict__ VT) {
    __shared__ __align__(16) char smem[3][2][8192];  // [buf][X,W][128 rows x 64B]
    int z = blockIdx.z;
    const unsigned short* Wz = WT + (size_t)z * 1024 * 1024;
    const float* bias = (z == 0) ? bq : ((z == 1) ? bk : bv);
    const int m0 = blockIdx.x * 128, n0 = blockIdx.y * 128;
    const int tid = threadIdx.x, lane = tid & 63, wid = tid >> 6;
    const int wr = wid >> 1, wc = wid & 1;
    const int g = lane >> 4, r16 = lane & 15;

    f32x4 acc[4][4] = {};

#define QSTAGE(BUFI, K0)                                                             \
    {                                                                                \
        _Pragma("unroll")                                                            \
        for (int p = 0; p < 2; ++p) {                                                \
            int row = p * 64 + (tid >> 2);                                           \
            int ec = ((tid & 3) ^ (row & 3)) * 8;                                    \
            size_t xo = (size_t)(m0 + row) * 1024 + (K0) + ec;                       \
            size_t wo = (size_t)(n0 + row) * 1024 + (K0) + ec;                       \
            gload16(XF + xo, &smem[(BUFI)][0][0] + p * 4096 + tid * 16);             \
            gload16(Wz + wo, &smem[(BUFI)][1][0] + p * 4096 + tid * 16);             \
        }                                                                            \
    }

    QSTAGE(0, 0);
    QSTAGE(1, 32);
    int bufc = 0, bufs = 2;
    for (int ki = 0; ki < 32; ++ki) {
        if (ki < 31) {
            asm volatile("s_waitcnt vmcnt(4)" ::: "memory");
        } else {
            asm volatile("s_waitcnt vmcnt(0)" ::: "memory");
        }
        __builtin_amdgcn_s_barrier();
        if (ki < 30) QSTAGE(bufs, (ki + 2) * 32);
        const char* bX = &smem[bufc][0][0];
        const char* bW = &smem[bufc][1][0];
        const int sx = (r16 & 3) << 4;

        f16x8 af[4], bf[4];
#pragma unroll
        for (int mi = 0; mi < 4; ++mi)
            af[mi] = *(const f16x8*)(bX + (wr * 64 + mi * 16 + r16) * 64 + ((g << 4) ^ sx));
#pragma unroll
        for (int ni = 0; ni < 4; ++ni)
            bf[ni] = *(const f16x8*)(bW + (wc * 64 + ni * 16 + r16) * 64 + ((g << 4) ^ sx));
        __builtin_amdgcn_s_setprio(1);
#pragma unroll
        for (int mi = 0; mi < 4; ++mi)
#pragma unroll
            for (int ni = 0; ni < 4; ++ni)
                acc[mi][ni] = MFMA16(af[mi], bf[ni], acc[mi][ni]);
        __builtin_amdgcn_s_setprio(0);
        bufc = (bufc == 2) ? 0 : bufc + 1;
        bufs = (bufs == 2) ? 0 : bufs + 1;
    }

    // epilogue: frag D row = g*4+r (m), col = r16 (n)
#pragma unroll
    for (int mi = 0; mi < 4; ++mi)
#pragma unroll
        for (int ni = 0; ni < 4; ++ni)
#pragma unroll
            for (int r = 0; r < 4; ++r) {
                int m = m0 + wr * 64 + mi * 16 + g * 4 + r;
                int n = n0 + wc * 64 + ni * 16 + r16;
                float val = acc[mi][ni][r] + bias[n];
                if (z == 0) val *= 0.18033688011112042f;  // 0.125 * log2(e)
                int b = m >> 11, s = m & 2047, hh = n >> 6, d = n & 63;
                unsigned short hv = f2h(val);
                if (z == 2) {
                    VT[((size_t)(b * 16 + hh) * 64 + d) * 2048 + s] = hv;
                } else {
                    size_t o = ((size_t)(b * 16 + hh) * 2048 + s) * 64 + d;
                    if (z == 0) QF[o] = hv; else KF[o] = hv;
                }
            }
}

// ---------------------------------------------------------------- attention (flash, 32x32 MFMA, f16)
// k-split decomposition: grid 1024 (XCD-swizzled), 4 waves = (qh x kh); each
// wave: 32 q-rows x 32 k-cols per chunk. QBLK=64, KVBLK=64, 2-deep LDS (36KB
// -> 4 blocks/CU = 4 waves/SIMD). Fixed-max softmax => ctx/l are pure sums;
// kh partials merged via LDS scratch at the end. One barrier/chunk.
__global__ __launch_bounds__(256, 4) void attn_kernel(
    const unsigned short* __restrict__ QF, const unsigned short* __restrict__ KF,
    const unsigned short* __restrict__ VT, const int* __restrict__ mask,
    float* __restrict__ out) {
    __shared__ __align__(16) char smem[2][2][8192];      // [buf][K,V][64 rows x 128B]
    __shared__ __align__(16) unsigned short cmlds[2048]; // f16 mask bias
    const int tid = threadIdx.x;
    const int lane = tid & 63, wid = tid >> 6;
    const int hi = lane >> 5, l31 = lane & 31;
    // XCD swizzle: 1024 blocks, 8 XCDs -> blocks sharing a head cluster on one XCD
    const int bid = blockIdx.x;
    const int wgid = (bid & 7) * 128 + (bid >> 3);
    const int bh = wgid >> 5, qb = wgid & 31;
    const int b = bh >> 4, h = bh & 15;
    const int qh = wid & 1, kh = wid >> 1;
    const size_t base = (size_t)bh * 2048 * 64;
    const unsigned short* KFh = KF + base;
    const unsigned short* VTh = VT + base;
    const int qrow = qb * 64 + qh * 32 + l31;
    const int swz = (l31 & 7) << 4;

    // Q fragments (B operand): lane holds q = l31, k-elems = ks*16 + hi*8 .. +7
    f16x8 qf[4];
#pragma unroll
    for (int ks = 0; ks < 4; ++ks)
        qf[ks] = *reinterpret_cast<const f16x8*>(QF + base + (size_t)qrow * 64 + ks * 16 + hi * 8);

    // staging: wave (pl=wid>>1, half=wid&1): 32 rows of plane pl, 4 loads.
    const int lr = lane >> 3, c16 = lane & 7;
    const int gce = (c16 ^ lr) << 3;
    const int pl = wid >> 1, half = wid & 1;
    const unsigned short* mys = pl ? VTh : KFh;
    const int rstr = pl ? 2048 : 64;

    f32x16 ctx[2] = {};
    float l_st = 0.f;

#define STAGE(BUFI, K0)                                                              \
    {                                                                                \
        char* dst = &smem[(BUFI)][pl][0] + half * 4096;                              \
        size_t koff = pl ? (size_t)(K0) : (size_t)(K0) * 64;                         \
        _Pragma("unroll")                                                            \
        for (int i = 0; i < 4; ++i) {                                                \
            int r = half * 32 + i * 8 + lr;                                          \
            gload16(mys + koff + (size_t)r * rstr + gce, dst + i * 1024 + lane * 16);\
        }                                                                            \
    }

    STAGE(0, 0);
    // cmask -> LDS f16 (c = mask ? -13 : -60000); overlaps staging flight
    {
        const int* mrow = mask + b * 2048;
        int4 m0v = *reinterpret_cast<const int4*>(mrow + tid * 8);
        int4 m1v = *reinterpret_cast<const int4*>(mrow + tid * 8 + 4);
        const unsigned short N13 = f2h(-13.f), BIG = f2h(-60000.f);
        ushort4 c0, c1;
        c0.x = m0v.x ? N13 : BIG; c0.y = m0v.y ? N13 : BIG;
        c0.z = m0v.z ? N13 : BIG; c0.w = m0v.w ? N13 : BIG;
        c1.x = m1v.x ? N13 : BIG; c1.y = m1v.y ? N13 : BIG;
        c1.z = m1v.z ? N13 : BIG; c1.w = m1v.w ? N13 : BIG;
        *reinterpret_cast<ushort4*>(&cmlds[tid * 8]) = c0;
        *reinterpret_cast<ushort4*>(&cmlds[tid * 8 + 4]) = c1;
    }

    for (int ch = 0; ch < 32; ++ch) {
        asm volatile("s_waitcnt vmcnt(0) lgkmcnt(0)" ::: "memory");
        __builtin_amdgcn_s_barrier();
        if (ch < 31) STAGE((ch + 1) & 1, (ch + 1) * 64);
        const int buf = ch & 1;
        const char* bK = &smem[buf][0][0];
        const char* bV = &smem[buf][1][0];
        const int k0s = ch * 64 + kh * 32;

        // ---- QK^T (swapped): A = K rows (kh window), B = Q -> D[k32][q32]
        f32x16 sc;
        {
            const char* rK = bK + (kh * 32 + l31) * 128;
            f32x16 a = {};
            __builtin_amdgcn_s_setprio(1);
#pragma unroll
            for (int ks = 0; ks < 4; ++ks)
                a = MFMA32(*(const f16x8*)(rK + ((ks * 32 + hi * 16) ^ swz)), qf[ks], a);
            __builtin_amdgcn_s_setprio(0);
            sc = a;
        }

        // ---- fixed-max softmax on 32-k window: p = exp2(s + c_k)
        float p[16];
        float psum = 0.f;
#pragma unroll
        for (int G = 0; G < 4; ++G) {
            ushort4 cu = *reinterpret_cast<const ushort4*>(&cmlds[k0s + 8 * G + 4 * hi]);
            int bo = G * 4;
            float e0 = __builtin_amdgcn_exp2f(sc[bo + 0] + h2f(cu.x));
            float e1 = __builtin_amdgcn_exp2f(sc[bo + 1] + h2f(cu.y));
            float e2 = __builtin_amdgcn_exp2f(sc[bo + 2] + h2f(cu.z));
            float e3 = __builtin_amdgcn_exp2f(sc[bo + 3] + h2f(cu.w));
            p[bo + 0] = e0; p[bo + 1] = e1; p[bo + 2] = e2; p[bo + 3] = e3;
            psum += e0 + e1 + e2 + e3;
        }
        l_st += psum;

        // ---- pack P (32 k) into 2 PV B-fragments (r8-proven shfl pack)
        f16x8 pf[2];
        {
            unsigned a0 = pk2f(p[0], p[1]),   a1 = pk2f(p[2], p[3]);
            unsigned b0 = pk2f(p[4], p[5]),   b1 = pk2f(p[6], p[7]);
            unsigned c0 = pk2f(p[8], p[9]),   c1 = pk2f(p[10], p[11]);
            unsigned d0 = pk2f(p[12], p[13]), d1 = pk2f(p[14], p[15]);
            unsigned ta0 = __shfl_xor((int)a0, 32), ta1 = __shfl_xor((int)a1, 32);
            unsigned tb0 = __shfl_xor((int)b0, 32), tb1 = __shfl_xor((int)b1, 32);
            unsigned tc0 = __shfl_xor((int)c0, 32), tc1 = __shfl_xor((int)c1, 32);
            unsigned td0 = __shfl_xor((int)d0, 32), td1 = __shfl_xor((int)d1, 32);
            union { unsigned u[4]; f16x8 v; } f0, f1;
            f0.u[0] = hi ? tb0 : a0; f0.u[1] = hi ? tb1 : a1;
            f0.u[2] = hi ? b0 : ta0; f0.u[3] = hi ? b1 : ta1;
            f1.u[0] = hi ? td0 : c0; f1.u[1] = hi ? td1 : c1;
            f1.u[2] = hi ? d0 : tc0; f1.u[3] = hi ? d1 : tc1;
            pf[0] = f0.v; pf[1] = f1.v;
        }

        // ---- PV (swapped): A = Vt rows (d), k-window kh -> D[d][q] partial
        __builtin_amdgcn_s_setprio(1);
#pragma unroll
        for (int dt = 0; dt < 2; ++dt) {
            const char* rV = bV + (dt * 32 + l31) * 128;
            f32x16 a = ctx[dt];
#pragma unroll
            for (int ks = 0; ks < 2; ++ks)
                a = MFMA32(*(const f16x8*)(rV + ((kh * 64 + ks * 32 + hi * 16) ^ swz)), pf[ks], a);
            ctx[dt] = a;
        }
        __builtin_amdgcn_s_setprio(0);
    }

    // ---- merge kh partials via LDS scratch (smem is free now)
    l_st += __shfl_xor(l_st, 32);
    __builtin_amdgcn_s_barrier();
    float* scr = (float*)&smem[0][0][0];
    if (kh) {
        float* dst = scr + qh * 2048 + lane * 32;
#pragma unroll
        for (int dt = 0; dt < 2; ++dt)
#pragma unroll
            for (int G = 0; G < 4; ++G) {
                float4 st;
                st.x = ctx[dt][G * 4 + 0]; st.y = ctx[dt][G * 4 + 1];
                st.z = ctx[dt][G * 4 + 2]; st.w = ctx[dt][G * 4 + 3];
                *reinterpret_cast<float4*>(dst + dt * 16 + G * 4) = st;
            }
        scr[4096 + qh * 64 + lane] = l_st;
    }
    __builtin_amdgcn_s_barrier();
    if (!kh) {
        const float* src = scr + qh * 2048 + lane * 32;
        float l_full = l_st + scr[4096 + qh * 64 + lane];
        float inv_l = 1.0f / l_full;
        size_t ob0 = ((size_t)b * 2048 + qrow) * 1024 + h * 64 + 4 * hi;
#pragma unroll
        for (int dt = 0; dt < 2; ++dt)
#pragma unroll
            for (int G = 0; G < 4; ++G) {
                float4 pv = *reinterpret_cast<const float4*>(src + dt * 16 + G * 4);
                float4 st;
                st.x = (ctx[dt][G * 4 + 0] + pv.x) * inv_l;
                st.y = (ctx[dt][G * 4 + 1] + pv.y) * inv_l;
                st.z = (ctx[dt][G * 4 + 2] + pv.z) * inv_l;
                st.w = (ctx[dt][G * 4 + 3] + pv.w) * inv_l;
                *reinterpret_cast<float4*>(out + ob0 + dt * 32 + 8 * G) = st;
            }
    }
}

// ---------------------------------------------------------------- launch
extern "C" void kernel_launch(void* const* d_in, const int* in_sizes, int n_in,
                              void* d_out, int out_size, void* d_ws, size_t ws_size,
                              hipStream_t stream) {
    const float* X  = (const float*)d_in[0];
    const int* mask = (const int*)d_in[1];
    const float* Wq = (const float*)d_in[2];
    const float* bq = (const float*)d_in[3];
    const float* Wk = (const float*)d_in[4];
    const float* bk = (const float*)d_in[5];
    const float* Wv = (const float*)d_in[6];
    const float* bv = (const float*)d_in[7];
    float* out = (float*)d_out;

    char* ws = (char*)d_ws;
    const size_t SZ_X = (size_t)4096 * 1024 * 2;        // 8 MB f16 X
    const size_t SZ_W = (size_t)1024 * 1024 * 2;        // 2 MB per W plane
    const size_t SZ_Q = (size_t)2 * 16 * 2048 * 64 * 2; // 8 MB per QKV plane
    unsigned short* XF = (unsigned short*)(ws);
    unsigned short* WT = (unsigned short*)(ws + SZ_X);
    unsigned short* QF = (unsigned short*)(ws + SZ_X + 3 * SZ_W);
    unsigned short* KF = (unsigned short*)(ws + SZ_X + 3 * SZ_W + 1 * SZ_Q);
    unsigned short* VT = (unsigned short*)(ws + SZ_X + 3 * SZ_W + 2 * SZ_Q);

    prep_x_kernel<<<4096, 256, 0, stream>>>(X, XF);
    prep_w_kernel<<<dim3(16, 16, 3), 256, 0, stream>>>(Wq, Wk, Wv, WT);
    qkv_gemm_kernel<<<dim3(32, 8, 3), 256, 0, stream>>>(XF, WT, bq, bk, bv, QF, KF, VT);
    attn_kernel<<<1024, 256, 0, stream>>>(QF, KF, VT, mask, out);
}

// Round 12
// 107.978 us; speedup vs baseline: 1.0875x; 1.0712x over previous
//
#include <hip/hip_runtime.h>
#include <math.h>

typedef __attribute__((ext_vector_type(4))) float f32x4;
typedef __attribute__((ext_vector_type(16))) float f32x16;
typedef _Float16 f16x8 __attribute__((ext_vector_type(8)));
typedef __fp16 fp16x2 __attribute__((ext_vector_type(2)));
typedef unsigned int uintv2 __attribute__((ext_vector_type(2)));

#define MFMA16(a, b, c) __builtin_amdgcn_mfma_f32_16x16x32_f16((a), (b), (c), 0, 0, 0)
#define MFMA32(a, b, c) __builtin_amdgcn_mfma_f32_32x32x16_f16((a), (b), (c), 0, 0, 0)

__device__ __forceinline__ unsigned short f2h(float f) {
    union { _Float16 h; unsigned short u; } v; v.h = (_Float16)f; return v.u;
}
__device__ __forceinline__ unsigned pk2f(float a, float b) {
    union { fp16x2 h; unsigned u; } v; v.h = __builtin_amdgcn_cvt_pkrtz(a, b); return v.u;
}

#if defined(__has_builtin)
#if __has_builtin(__builtin_amdgcn_global_load_lds)
#define HAVE_GLL 1
#endif
#endif

__device__ __forceinline__ void gload16(const void* g, void* lds) {
#ifdef HAVE_GLL
    __builtin_amdgcn_global_load_lds(
        (const __attribute__((address_space(1))) void*)g,
        (__attribute__((address_space(3))) void*)lds, 16, 0, 0);
#else
    *(f16x8*)lds = *(const f16x8*)g;
#endif
}

// ---------------------------------------------------------------- prep X (f32 -> f16)
__global__ __launch_bounds__(256) void prep_x_kernel(
    const float* __restrict__ X, unsigned short* __restrict__ XF) {
    int i = (blockIdx.x * 256 + threadIdx.x) * 4;
    float4 v = *reinterpret_cast<const float4*>(X + i);
    ushort4 h;
    h.x = f2h(v.x); h.y = f2h(v.y); h.z = f2h(v.z); h.w = f2h(v.w);
    *reinterpret_cast<ushort4*>(XF + i) = h;
}

// ---------------------------------------------------------------- prep W (transpose + f16)
__global__ __launch_bounds__(256) void prep_w_kernel(
    const float* __restrict__ Wq, const float* __restrict__ Wk,
    const float* __restrict__ Wv, unsigned short* __restrict__ WT) {
    __shared__ float T[64][65];
    int z = blockIdx.z;
    const float* W = (z == 0) ? Wq : ((z == 1) ? Wk : Wv);
    unsigned short* Wo = WT + (size_t)z * 1024 * 1024;
    int k0 = blockIdx.x * 64, n0 = blockIdx.y * 64;
    int t = threadIdx.x;
    for (int i = 0; i < 4; i++) {
        int fid = t + i * 256;
        int rr = fid >> 4, cc = fid & 15;
        float4 v = *reinterpret_cast<const float4*>(W + (size_t)(k0 + rr) * 1024 + n0 + cc * 4);
        T[rr][cc * 4 + 0] = v.x; T[rr][cc * 4 + 1] = v.y;
        T[rr][cc * 4 + 2] = v.z; T[rr][cc * 4 + 3] = v.w;
    }
    __syncthreads();
    for (int i = 0; i < 4; i++) {
        int e = t + i * 256;
        int n = e >> 4, kq = (e & 15) * 4;
        ushort4 h;
        h.x = f2h(T[kq + 0][n]); h.y = f2h(T[kq + 1][n]);
        h.z = f2h(T[kq + 2][n]); h.w = f2h(T[kq + 3][n]);
        size_t o = (size_t)(n0 + n) * 1024 + k0 + kq;
        *reinterpret_cast<ushort4*>(Wo + o) = h;
    }
}

// ---------------------------------------------------------------- QKV GEMM (f16, counted-vmcnt pipeline)
// 128x128 tile, BK=32, 3-deep LDS (48KB -> 3 blocks/CU), 4 waves x (64x64).
__global__ __launch_bounds__(256, 3) void qkv_gemm_kernel(
    const unsigned short* __restrict__ XF, const unsigned short* __restrict__ WT,
    const float* __restrict__ bq, const float* __restrict__ bk,
    const float* __restrict__ bv,
    unsigned short* __restrict__ QF, unsigned short* __restrict__ KF,
    unsigned short* __restrict__ VT) {
    __shared__ __align__(16) char smem[3][2][8192];  // [buf][X,W][128 rows x 64B]
    int z = blockIdx.z;
    const unsigned short* Wz = WT + (size_t)z * 1024 * 1024;
    const float* bias = (z == 0) ? bq : ((z == 1) ? bk : bv);
    const int m0 = blockIdx.x * 128, n0 = blockIdx.y * 128;
    const int tid = threadIdx.x, lane = tid & 63, wid = tid >> 6;
    const int wr = wid >> 1, wc = wid & 1;
    const int g = lane >> 4, r16 = lane & 15;

    f32x4 acc[4][4] = {};

#define QSTAGE(BUFI, K0)                                                             \
    {                                                                                \
        _Pragma("unroll")                                                            \
        for (int p = 0; p < 2; ++p) {                                                \
            int row = p * 64 + (tid >> 2);                                           \
            int ec = ((tid & 3) ^ (row & 3)) * 8;                                    \
            size_t xo = (size_t)(m0 + row) * 1024 + (K0) + ec;                       \
            size_t wo = (size_t)(n0 + row) * 1024 + (K0) + ec;                       \
            gload16(XF + xo, &smem[(BUFI)][0][0] + p * 4096 + tid * 16);             \
            gload16(Wz + wo, &smem[(BUFI)][1][0] + p * 4096 + tid * 16);             \
        }                                                                            \
    }

    QSTAGE(0, 0);
    QSTAGE(1, 32);
    int bufc = 0, bufs = 2;
    for (int ki = 0; ki < 32; ++ki) {
        if (ki < 31) {
            asm volatile("s_waitcnt vmcnt(4)" ::: "memory");
        } else {
            asm volatile("s_waitcnt vmcnt(0)" ::: "memory");
        }
        __builtin_amdgcn_s_barrier();
        if (ki < 30) QSTAGE(bufs, (ki + 2) * 32);
        const char* bX = &smem[bufc][0][0];
        const char* bW = &smem[bufc][1][0];
        const int sx = (r16 & 3) << 4;

        f16x8 af[4], bf[4];
#pragma unroll
        for (int mi = 0; mi < 4; ++mi)
            af[mi] = *(const f16x8*)(bX + (wr * 64 + mi * 16 + r16) * 64 + ((g << 4) ^ sx));
#pragma unroll
        for (int ni = 0; ni < 4; ++ni)
            bf[ni] = *(const f16x8*)(bW + (wc * 64 + ni * 16 + r16) * 64 + ((g << 4) ^ sx));
        __builtin_amdgcn_s_setprio(1);
#pragma unroll
        for (int mi = 0; mi < 4; ++mi)
#pragma unroll
            for (int ni = 0; ni < 4; ++ni)
                acc[mi][ni] = MFMA16(af[mi], bf[ni], acc[mi][ni]);
        __builtin_amdgcn_s_setprio(0);
        bufc = (bufc == 2) ? 0 : bufc + 1;
        bufs = (bufs == 2) ? 0 : bufs + 1;
    }

    // epilogue: frag D row = g*4+r (m), col = r16 (n)
#pragma unroll
    for (int mi = 0; mi < 4; ++mi)
#pragma unroll
        for (int ni = 0; ni < 4; ++ni)
#pragma unroll
            for (int r = 0; r < 4; ++r) {
                int m = m0 + wr * 64 + mi * 16 + g * 4 + r;
                int n = n0 + wc * 64 + ni * 16 + r16;
                float val = acc[mi][ni][r] + bias[n];
                if (z == 0) val *= 0.18033688011112042f;  // 0.125 * log2(e)
                int b = m >> 11, s = m & 2047, hh = n >> 6, d = n & 63;
                unsigned short hv = f2h(val);
                if (z == 2) {
                    VT[((size_t)(b * 16 + hh) * 64 + d) * 2048 + s] = hv;
                } else {
                    size_t o = ((size_t)(b * 16 + hh) * 2048 + s) * 64 + d;
                    if (z == 0) QF[o] = hv; else KF[o] = hv;
                }
            }
}

// ---------------------------------------------------------------- attention (flash, 32x32 MFMA, f16)
// k-split: grid 1024 (XCD-swizzled), 4 waves = (qh x kh), 32q x 32k per wave.
// 2-deep LDS (40KB -> 4 blocks/CU). f32 cmask in LDS; permlane32_swap P-pack.
__global__ __launch_bounds__(256, 4) void attn_kernel(
    const unsigned short* __restrict__ QF, const unsigned short* __restrict__ KF,
    const unsigned short* __restrict__ VT, const int* __restrict__ mask,
    float* __restrict__ out) {
    __shared__ __align__(16) char smem[2][2][8192];  // [buf][K,V][64 rows x 128B]
    __shared__ __align__(16) float cmlds[2048];      // f32 mask bias
    const int tid = threadIdx.x;
    const int lane = tid & 63, wid = tid >> 6;
    const int hi = lane >> 5, l31 = lane & 31;
    const int bid = blockIdx.x;
    const int wgid = (bid & 7) * 128 + (bid >> 3);
    const int bh = wgid >> 5, qb = wgid & 31;
    const int b = bh >> 4, h = bh & 15;
    const int qh = wid & 1, kh = wid >> 1;
    const size_t base = (size_t)bh * 2048 * 64;
    const unsigned short* KFh = KF + base;
    const unsigned short* VTh = VT + base;
    const int qrow = qb * 64 + qh * 32 + l31;
    const int swz = (l31 & 7) << 4;

    // Q fragments (B operand): lane holds q = l31, k-elems = ks*16 + hi*8 .. +7
    f16x8 qf[4];
#pragma unroll
    for (int ks = 0; ks < 4; ++ks)
        qf[ks] = *reinterpret_cast<const f16x8*>(QF + base + (size_t)qrow * 64 + ks * 16 + hi * 8);

    // staging: wave (pl=wid>>1, half=wid&1): 32 rows of plane pl, 4 loads.
    const int lr = lane >> 3, c16 = lane & 7;
    const int gce = (c16 ^ lr) << 3;
    const int pl = wid >> 1, half = wid & 1;
    const unsigned short* mys = pl ? VTh : KFh;
    const int rstr = pl ? 2048 : 64;

    f32x16 ctx[2] = {};
    float l_st = 0.f;

#define STAGE(BUFI, K0)                                                              \
    {                                                                                \
        char* dst = &smem[(BUFI)][pl][0] + half * 4096;                              \
        size_t koff = pl ? (size_t)(K0) : (size_t)(K0) * 64;                         \
        _Pragma("unroll")                                                            \
        for (int i = 0; i < 4; ++i) {                                                \
            int r = half * 32 + i * 8 + lr;                                          \
            gload16(mys + koff + (size_t)r * rstr + gce, dst + i * 1024 + lane * 16);\
        }                                                                            \
    }

    STAGE(0, 0);
    // cmask -> LDS f32 (c = mask ? -13 : -1e9); overlaps staging flight
    {
        const int* mrow = mask + b * 2048;
        int4 m0v = *reinterpret_cast<const int4*>(mrow + tid * 8);
        int4 m1v = *reinterpret_cast<const int4*>(mrow + tid * 8 + 4);
        float4 c0, c1;
        c0.x = m0v.x ? -13.f : -1e9f; c0.y = m0v.y ? -13.f : -1e9f;
        c0.z = m0v.z ? -13.f : -1e9f; c0.w = m0v.w ? -13.f : -1e9f;
        c1.x = m1v.x ? -13.f : -1e9f; c1.y = m1v.y ? -13.f : -1e9f;
        c1.z = m1v.z ? -13.f : -1e9f; c1.w = m1v.w ? -13.f : -1e9f;
        *reinterpret_cast<float4*>(&cmlds[tid * 8]) = c0;
        *reinterpret_cast<float4*>(&cmlds[tid * 8 + 4]) = c1;
    }

    for (int ch = 0; ch < 32; ++ch) {
        asm volatile("s_waitcnt vmcnt(0) lgkmcnt(0)" ::: "memory");
        __builtin_amdgcn_s_barrier();
        if (ch < 31) STAGE((ch + 1) & 1, (ch + 1) * 64);
        const int buf = ch & 1;
        const char* bK = &smem[buf][0][0];
        const char* bV = &smem[buf][1][0];
        const int k0s = ch * 64 + kh * 32;

        // ---- QK^T (swapped): A = K rows (kh window), B = Q -> D[k32][q32]
        f32x16 sc;
        {
            const char* rK = bK + (kh * 32 + l31) * 128;
            f32x16 a = {};
            __builtin_amdgcn_s_setprio(1);
#pragma unroll
            for (int ks = 0; ks < 4; ++ks)
                a = MFMA32(*(const f16x8*)(rK + ((ks * 32 + hi * 16) ^ swz)), qf[ks], a);
            __builtin_amdgcn_s_setprio(0);
            sc = a;
        }

        // ---- fixed-max softmax on 32-k window: p = exp2(s + c_k)
        float p[16];
        float psum = 0.f;
#pragma unroll
        for (int G = 0; G < 4; ++G) {
            float4 cv = *reinterpret_cast<const float4*>(&cmlds[k0s + 8 * G + 4 * hi]);
            int bo = G * 4;
            float e0 = __builtin_amdgcn_exp2f(sc[bo + 0] + cv.x);
            float e1 = __builtin_amdgcn_exp2f(sc[bo + 1] + cv.y);
            float e2 = __builtin_amdgcn_exp2f(sc[bo + 2] + cv.z);
            float e3 = __builtin_amdgcn_exp2f(sc[bo + 3] + cv.w);
            p[bo + 0] = e0; p[bo + 1] = e1; p[bo + 2] = e2; p[bo + 3] = e3;
            psum += e0 + e1 + e2 + e3;
        }
        l_st += psum;

        // ---- pack P (32 k) into 2 PV B-fragments via permlane32_swap
        // r = swap(a,b): r[0] = {a.lo, b.lo}, r[1] = {a.hi, b.hi}
        f16x8 pf[2];
        {
            unsigned a0 = pk2f(p[0], p[1]),   a1 = pk2f(p[2], p[3]);
            unsigned b0 = pk2f(p[4], p[5]),   b1 = pk2f(p[6], p[7]);
            unsigned c0 = pk2f(p[8], p[9]),   c1 = pk2f(p[10], p[11]);
            unsigned d0 = pk2f(p[12], p[13]), d1 = pk2f(p[14], p[15]);
            uintv2 r0 = __builtin_amdgcn_permlane32_swap(a0, b0, false, false);
            uintv2 r1 = __builtin_amdgcn_permlane32_swap(a1, b1, false, false);
            uintv2 r2 = __builtin_amdgcn_permlane32_swap(c0, d0, false, false);
            uintv2 r3 = __builtin_amdgcn_permlane32_swap(c1, d1, false, false);
            union { unsigned u[4]; f16x8 v; } f0, f1;
            f0.u[0] = r0[0]; f0.u[1] = r1[0]; f0.u[2] = r0[1]; f0.u[3] = r1[1];
            f1.u[0] = r2[0]; f1.u[1] = r3[0]; f1.u[2] = r2[1]; f1.u[3] = r3[1];
            pf[0] = f0.v; pf[1] = f1.v;
        }

        // ---- PV (swapped): A = Vt rows (d), k-window kh -> D[d][q] partial
        __builtin_amdgcn_s_setprio(1);
#pragma unroll
        for (int dt = 0; dt < 2; ++dt) {
            const char* rV = bV + (dt * 32 + l31) * 128;
            f32x16 a = ctx[dt];
#pragma unroll
            for (int ks = 0; ks < 2; ++ks)
                a = MFMA32(*(const f16x8*)(rV + ((kh * 64 + ks * 32 + hi * 16) ^ swz)), pf[ks], a);
            ctx[dt] = a;
        }
        __builtin_amdgcn_s_setprio(0);
    }

    // ---- merge kh partials via LDS scratch (stride 36 dwords: no 32-way conflict)
    l_st += __shfl_xor(l_st, 32);
    __builtin_amdgcn_s_barrier();
    float* scr = (float*)&smem[0][0][0];
    if (kh) {
        float* dst = scr + qh * 2304 + lane * 36;
#pragma unroll
        for (int dt = 0; dt < 2; ++dt)
#pragma unroll
            for (int G = 0; G < 4; ++G) {
                float4 st;
                st.x = ctx[dt][G * 4 + 0]; st.y = ctx[dt][G * 4 + 1];
                st.z = ctx[dt][G * 4 + 2]; st.w = ctx[dt][G * 4 + 3];
                *reinterpret_cast<float4*>(dst + dt * 16 + G * 4) = st;
            }
        scr[4608 + qh * 64 + lane] = l_st;
    }
    __builtin_amdgcn_s_barrier();
    if (!kh) {
        const float* src = scr + qh * 2304 + lane * 36;
        float l_full = l_st + scr[4608 + qh * 64 + lane];
        float inv_l = 1.0f / l_full;
        size_t ob0 = ((size_t)b * 2048 + qrow) * 1024 + h * 64 + 4 * hi;
#pragma unroll
        for (int dt = 0; dt < 2; ++dt)
#pragma unroll
            for (int G = 0; G < 4; ++G) {
                float4 pv = *reinterpret_cast<const float4*>(src + dt * 16 + G * 4);
                float4 st;
                st.x = (ctx[dt][G * 4 + 0] + pv.x) * inv_l;
                st.y = (ctx[dt][G * 4 + 1] + pv.y) * inv_l;
                st.z = (ctx[dt][G * 4 + 2] + pv.z) * inv_l;
                st.w = (ctx[dt][G * 4 + 3] + pv.w) * inv_l;
                *reinterpret_cast<float4*>(out + ob0 + dt * 32 + 8 * G) = st;
            }
    }
}

// ---------------------------------------------------------------- launch
extern "C" void kernel_launch(void* const* d_in, const int* in_sizes, int n_in,
                              void* d_out, int out_size, void* d_ws, size_t ws_size,
                              hipStream_t stream) {
    const float* X  = (const float*)d_in[0];
    const int* mask = (const int*)d_in[1];
    const float* Wq = (const float*)d_in[2];
    const float* bq = (const float*)d_in[3];
    const float* Wk = (const float*)d_in[4];
    const float* bk = (const float*)d_in[5];
    const float* Wv = (const float*)d_in[6];
    const float* bv = (const float*)d_in[7];
    float* out = (float*)d_out;

    char* ws = (char*)d_ws;
    const size_t SZ_X = (size_t)4096 * 1024 * 2;        // 8 MB f16 X
    const size_t SZ_W = (size_t)1024 * 1024 * 2;        // 2 MB per W plane
    const size_t SZ_Q = (size_t)2 * 16 * 2048 * 64 * 2; // 8 MB per QKV plane
    unsigned short* XF = (unsigned short*)(ws);
    unsigned short* WT = (unsigned short*)(ws + SZ_X);
    unsigned short* QF = (unsigned short*)(ws + SZ_X + 3 * SZ_W);
    unsigned short* KF = (unsigned short*)(ws + SZ_X + 3 * SZ_W + 1 * SZ_Q);
    unsigned short* VT = (unsigned short*)(ws + SZ_X + 3 * SZ_W + 2 * SZ_Q);

    prep_x_kernel<<<4096, 256, 0, stream>>>(X, XF);
    prep_w_kernel<<<dim3(16, 16, 3), 256, 0, stream>>>(Wq, Wk, Wv, WT);
    qkv_gemm_kernel<<<dim3(32, 8, 3), 256, 0, stream>>>(XF, WT, bq, bk, bv, QF, KF, VT);
    attn_kernel<<<1024, 256, 0, stream>>>(QF, KF, VT, mask, out);
}

// Round 13
// 107.236 us; speedup vs baseline: 1.0950x; 1.0069x over previous
//
#include <hip/hip_runtime.h>
#include <math.h>

typedef __attribute__((ext_vector_type(4))) float f32x4;
typedef __attribute__((ext_vector_type(16))) float f32x16;
typedef _Float16 f16x8 __attribute__((ext_vector_type(8)));
typedef __fp16 fp16x2 __attribute__((ext_vector_type(2)));
typedef unsigned int uintv2 __attribute__((ext_vector_type(2)));

#define MFMA16(a, b, c) __builtin_amdgcn_mfma_f32_16x16x32_f16((a), (b), (c), 0, 0, 0)
#define MFMA32(a, b, c) __builtin_amdgcn_mfma_f32_32x32x16_f16((a), (b), (c), 0, 0, 0)

__device__ __forceinline__ unsigned short f2h(float f) {
    union { _Float16 h; unsigned short u; } v; v.h = (_Float16)f; return v.u;
}
__device__ __forceinline__ unsigned pk2f(float a, float b) {
    union { fp16x2 h; unsigned u; } v; v.h = __builtin_amdgcn_cvt_pkrtz(a, b); return v.u;
}

#if defined(__has_builtin)
#if __has_builtin(__builtin_amdgcn_global_load_lds)
#define HAVE_GLL 1
#endif
#endif

__device__ __forceinline__ void gload16(const void* g, void* lds) {
#ifdef HAVE_GLL
    __builtin_amdgcn_global_load_lds(
        (const __attribute__((address_space(1))) void*)g,
        (__attribute__((address_space(3))) void*)lds, 16, 0, 0);
#else
    *(f16x8*)lds = *(const f16x8*)g;
#endif
}

// ---------------------------------------------------------------- merged prep:
// blocks [0,4096): X f32->f16 ; blocks [4096,4864): W transpose+f16.
__global__ __launch_bounds__(256) void prep_kernel(
    const float* __restrict__ X, const float* __restrict__ Wq,
    const float* __restrict__ Wk, const float* __restrict__ Wv,
    unsigned short* __restrict__ XF, unsigned short* __restrict__ WT) {
    __shared__ float T[64][65];
    const int bid = blockIdx.x, t = threadIdx.x;
    if (bid < 4096) {
        int i = (bid * 256 + t) * 4;
        float4 v = *reinterpret_cast<const float4*>(X + i);
        ushort4 h;
        h.x = f2h(v.x); h.y = f2h(v.y); h.z = f2h(v.z); h.w = f2h(v.w);
        *reinterpret_cast<ushort4*>(XF + i) = h;
        return;
    }
    const int t2 = bid - 4096;
    const int z = t2 >> 8, rem = t2 & 255;
    const int k0 = (rem & 15) * 64, n0 = (rem >> 4) * 64;
    const float* W = (z == 0) ? Wq : ((z == 1) ? Wk : Wv);
    unsigned short* Wo = WT + (size_t)z * 1024 * 1024;
    for (int i = 0; i < 4; i++) {
        int fid = t + i * 256;
        int rr = fid >> 4, cc = fid & 15;
        float4 v = *reinterpret_cast<const float4*>(W + (size_t)(k0 + rr) * 1024 + n0 + cc * 4);
        T[rr][cc * 4 + 0] = v.x; T[rr][cc * 4 + 1] = v.y;
        T[rr][cc * 4 + 2] = v.z; T[rr][cc * 4 + 3] = v.w;
    }
    __syncthreads();
    for (int i = 0; i < 4; i++) {
        int e = t + i * 256;
        int n = e >> 4, kq = (e & 15) * 4;
        ushort4 h;
        h.x = f2h(T[kq + 0][n]); h.y = f2h(T[kq + 1][n]);
        h.z = f2h(T[kq + 2][n]); h.w = f2h(T[kq + 3][n]);
        size_t o = (size_t)(n0 + n) * 1024 + k0 + kq;
        *reinterpret_cast<ushort4*>(Wo + o) = h;
    }
}

// ---------------------------------------------------------------- QKV GEMM (f16, counted-vmcnt pipeline)
// 128x128 tile, BK=32, 3-deep LDS (48KB -> 3 blocks/CU), 4 waves x (64x64).
__global__ __launch_bounds__(256, 3) void qkv_gemm_kernel(
    const unsigned short* __restrict__ XF, const unsigned short* __restrict__ WT,
    const float* __restrict__ bq, const float* __restrict__ bk,
    const float* __restrict__ bv,
    unsigned short* __restrict__ QF, unsigned short* __restrict__ KF,
    unsigned short* __restrict__ VT) {
    __shared__ __align__(16) char smem[3][2][8192];  // [buf][X,W][128 rows x 64B]
    int z = blockIdx.z;
    const unsigned short* Wz = WT + (size_t)z * 1024 * 1024;
    const float* bias = (z == 0) ? bq : ((z == 1) ? bk : bv);
    const int m0 = blockIdx.x * 128, n0 = blockIdx.y * 128;
    const int tid = threadIdx.x, lane = tid & 63, wid = tid >> 6;
    const int wr = wid >> 1, wc = wid & 1;
    const int g = lane >> 4, r16 = lane & 15;

    f32x4 acc[4][4] = {};

#define QSTAGE(BUFI, K0)                                                             \
    {                                                                                \
        _Pragma("unroll")                                                            \
        for (int p = 0; p < 2; ++p) {                                                \
            int row = p * 64 + (tid >> 2);                                           \
            int ec = ((tid & 3) ^ (row & 3)) * 8;                                    \
            size_t xo = (size_t)(m0 + row) * 1024 + (K0) + ec;                       \
            size_t wo = (size_t)(n0 + row) * 1024 + (K0) + ec;                       \
            gload16(XF + xo, &smem[(BUFI)][0][0] + p * 4096 + tid * 16);             \
            gload16(Wz + wo, &smem[(BUFI)][1][0] + p * 4096 + tid * 16);             \
        }                                                                            \
    }

    QSTAGE(0, 0);
    QSTAGE(1, 32);
    int bufc = 0, bufs = 2;
    for (int ki = 0; ki < 32; ++ki) {
        if (ki < 31) {
            asm volatile("s_waitcnt vmcnt(4)" ::: "memory");
        } else {
            asm volatile("s_waitcnt vmcnt(0)" ::: "memory");
        }
        __builtin_amdgcn_s_barrier();
        if (ki < 30) QSTAGE(bufs, (ki + 2) * 32);
        const char* bX = &smem[bufc][0][0];
        const char* bW = &smem[bufc][1][0];
        const int sx = (r16 & 3) << 4;

        f16x8 af[4], bf[4];
#pragma unroll
        for (int mi = 0; mi < 4; ++mi)
            af[mi] = *(const f16x8*)(bX + (wr * 64 + mi * 16 + r16) * 64 + ((g << 4) ^ sx));
#pragma unroll
        for (int ni = 0; ni < 4; ++ni)
            bf[ni] = *(const f16x8*)(bW + (wc * 64 + ni * 16 + r16) * 64 + ((g << 4) ^ sx));
        __builtin_amdgcn_s_setprio(1);
#pragma unroll
        for (int mi = 0; mi < 4; ++mi)
#pragma unroll
            for (int ni = 0; ni < 4; ++ni)
                acc[mi][ni] = MFMA16(af[mi], bf[ni], acc[mi][ni]);
        __builtin_amdgcn_s_setprio(0);
        bufc = (bufc == 2) ? 0 : bufc + 1;
        bufs = (bufs == 2) ? 0 : bufs + 1;
    }

    // epilogue: frag D row = g*4+r (m), col = r16 (n)
#pragma unroll
    for (int mi = 0; mi < 4; ++mi)
#pragma unroll
        for (int ni = 0; ni < 4; ++ni)
#pragma unroll
            for (int r = 0; r < 4; ++r) {
                int m = m0 + wr * 64 + mi * 16 + g * 4 + r;
                int n = n0 + wc * 64 + ni * 16 + r16;
                float val = acc[mi][ni][r] + bias[n];
                if (z == 0) val *= 0.18033688011112042f;  // 0.125 * log2(e)
                int b = m >> 11, s = m & 2047, hh = n >> 6, d = n & 63;
                unsigned short hv = f2h(val);
                if (z == 2) {
                    VT[((size_t)(b * 16 + hh) * 64 + d) * 2048 + s] = hv;
                } else {
                    size_t o = ((size_t)(b * 16 + hh) * 2048 + s) * 64 + d;
                    if (z == 0) QF[o] = hv; else KF[o] = hv;
                }
            }
}

// ---------------------------------------------------------------- attention (flash, 32x32 MFMA, f16)
// k-split: grid 1024 (XCD-swizzled), 4 waves = (qh x kh), 32q x 32k per wave.
// 2-deep LDS (40KB -> 4 blocks/CU). Unrolled x2 (static buf). l via ones-MFMA.
__global__ __launch_bounds__(256, 4) void attn_kernel(
    const unsigned short* __restrict__ QF, const unsigned short* __restrict__ KF,
    const unsigned short* __restrict__ VT, const int* __restrict__ mask,
    float* __restrict__ out) {
    __shared__ __align__(16) char smem[2][2][8192];  // [buf][K,V][64 rows x 128B]
    __shared__ __align__(16) float cmlds[2048];      // f32 mask bias
    const int tid = threadIdx.x;
    const int lane = tid & 63, wid = tid >> 6;
    const int hi = lane >> 5, l31 = lane & 31;
    const int bid = blockIdx.x;
    const int wgid = (bid & 7) * 128 + (bid >> 3);
    const int bh = wgid >> 5, qb = wgid & 31;
    const int b = bh >> 4, h = bh & 15;
    const int qh = wid & 1, kh = wid >> 1;
    const size_t base = (size_t)bh * 2048 * 64;
    const unsigned short* KFh = KF + base;
    const unsigned short* VTh = VT + base;
    const int qrow = qb * 64 + qh * 32 + l31;
    const int swz = (l31 & 7) << 4;

    // Q fragments (B operand): lane holds q = l31, k-elems = ks*16 + hi*8 .. +7
    f16x8 qf[4];
#pragma unroll
    for (int ks = 0; ks < 4; ++ks)
        qf[ks] = *reinterpret_cast<const f16x8*>(QF + base + (size_t)qrow * 64 + ks * 16 + hi * 8);

    // all-ones A fragment for the l-accumulation MFMA
    f16x8 onesf;
    {
        union { unsigned u[4]; f16x8 v; } o;
        o.u[0] = 0x3C003C00u; o.u[1] = 0x3C003C00u;
        o.u[2] = 0x3C003C00u; o.u[3] = 0x3C003C00u;
        onesf = o.v;
    }

    // staging: wave (pl=wid>>1, half=wid&1): 32 rows of plane pl, 4 loads.
    const int lr = lane >> 3, c16 = lane & 7;
    const int gce = (c16 ^ lr) << 3;
    const int pl = wid >> 1, half = wid & 1;
    const unsigned short* mys = pl ? VTh : KFh;
    const int rstr = pl ? 2048 : 64;

    f32x16 ctx[2] = {};
    f32x16 lacc = {};

#define STAGE(BUFI, K0)                                                              \
    {                                                                                \
        char* dst = &smem[(BUFI)][pl][0] + half * 4096;                              \
        size_t koff = pl ? (size_t)(K0) : (size_t)(K0) * 64;                         \
        _Pragma("unroll")                                                            \
        for (int i = 0; i < 4; ++i) {                                                \
            int r = half * 32 + i * 8 + lr;                                          \
            gload16(mys + koff + (size_t)r * rstr + gce, dst + i * 1024 + lane * 16);\
        }                                                                            \
    }

#define CHUNK(CH, BUF, NBUF)                                                         \
    {                                                                                \
        asm volatile("s_waitcnt vmcnt(0) lgkmcnt(0)" ::: "memory");                  \
        __builtin_amdgcn_s_barrier();                                                \
        if ((CH) < 31) STAGE(NBUF, ((CH) + 1) * 64);                                 \
        const char* bK = &smem[BUF][0][0];                                           \
        const char* bV = &smem[BUF][1][0];                                           \
        const int k0s = (CH) * 64 + kh * 32;                                         \
        f32x16 sc;                                                                   \
        {                                                                            \
            const char* rK = bK + (kh * 32 + l31) * 128;                             \
            f32x16 a = {};                                                           \
            __builtin_amdgcn_s_setprio(1);                                           \
            _Pragma("unroll")                                                        \
            for (int ks = 0; ks < 4; ++ks)                                           \
                a = MFMA32(*(const f16x8*)(rK + ((ks * 32 + hi * 16) ^ swz)),        \
                           qf[ks], a);                                               \
            __builtin_amdgcn_s_setprio(0);                                           \
            sc = a;                                                                  \
        }                                                                            \
        float p[16];                                                                 \
        _Pragma("unroll")                                                            \
        for (int G = 0; G < 4; ++G) {                                                \
            float4 cv = *reinterpret_cast<const float4*>(                            \
                &cmlds[k0s + 8 * G + 4 * hi]);                                       \
            int bo = G * 4;                                                          \
            p[bo + 0] = __builtin_amdgcn_exp2f(sc[bo + 0] + cv.x);                   \
            p[bo + 1] = __builtin_amdgcn_exp2f(sc[bo + 1] + cv.y);                   \
            p[bo + 2] = __builtin_amdgcn_exp2f(sc[bo + 2] + cv.z);                   \
            p[bo + 3] = __builtin_amdgcn_exp2f(sc[bo + 3] + cv.w);                   \
        }                                                                            \
        f16x8 pf[2];                                                                 \
        {                                                                            \
            unsigned a0 = pk2f(p[0], p[1]),   a1 = pk2f(p[2], p[3]);                 \
            unsigned b0 = pk2f(p[4], p[5]),   b1 = pk2f(p[6], p[7]);                 \
            unsigned c0 = pk2f(p[8], p[9]),   c1 = pk2f(p[10], p[11]);               \
            unsigned d0 = pk2f(p[12], p[13]), d1 = pk2f(p[14], p[15]);               \
            uintv2 r0 = __builtin_amdgcn_permlane32_swap(a0, b0, false, false);      \
            uintv2 r1 = __builtin_amdgcn_permlane32_swap(a1, b1, false, false);      \
            uintv2 r2 = __builtin_amdgcn_permlane32_swap(c0, d0, false, false);      \
            uintv2 r3 = __builtin_amdgcn_permlane32_swap(c1, d1, false, false);      \
            union { unsigned u[4]; f16x8 v; } f0, f1;                                \
            f0.u[0] = r0[0]; f0.u[1] = r1[0]; f0.u[2] = r0[1]; f0.u[3] = r1[1];      \
            f1.u[0] = r2[0]; f1.u[1] = r3[0]; f1.u[2] = r2[1]; f1.u[3] = r3[1];      \
            pf[0] = f0.v; pf[1] = f1.v;                                              \
        }                                                                            \
        __builtin_amdgcn_s_setprio(1);                                               \
        _Pragma("unroll")                                                            \
        for (int dt = 0; dt < 2; ++dt) {                                             \
            const char* rV = bV + (dt * 32 + l31) * 128;                             \
            f32x16 a = ctx[dt];                                                      \
            _Pragma("unroll")                                                        \
            for (int ks = 0; ks < 2; ++ks)                                           \
                a = MFMA32(*(const f16x8*)(rV +                                      \
                        ((kh * 64 + ks * 32 + hi * 16) ^ swz)), pf[ks], a);          \
            ctx[dt] = a;                                                             \
        }                                                                            \
        lacc = MFMA32(onesf, pf[0], lacc);                                           \
        lacc = MFMA32(onesf, pf[1], lacc);                                           \
        __builtin_amdgcn_s_setprio(0);                                               \
    }

    STAGE(0, 0);
    // cmask -> LDS f32 (c = mask ? -13 : -1e9); overlaps staging flight
    {
        const int* mrow = mask + b * 2048;
        int4 m0v = *reinterpret_cast<const int4*>(mrow + tid * 8);
        int4 m1v = *reinterpret_cast<const int4*>(mrow + tid * 8 + 4);
        float4 c0, c1;
        c0.x = m0v.x ? -13.f : -1e9f; c0.y = m0v.y ? -13.f : -1e9f;
        c0.z = m0v.z ? -13.f : -1e9f; c0.w = m0v.w ? -13.f : -1e9f;
        c1.x = m1v.x ? -13.f : -1e9f; c1.y = m1v.y ? -13.f : -1e9f;
        c1.z = m1v.z ? -13.f : -1e9f; c1.w = m1v.w ? -13.f : -1e9f;
        *reinterpret_cast<float4*>(&cmlds[tid * 8]) = c0;
        *reinterpret_cast<float4*>(&cmlds[tid * 8 + 4]) = c1;
    }

    for (int ch = 0; ch < 32; ch += 2) {
        CHUNK(ch, 0, 1);
        CHUNK(ch + 1, 1, 0);
    }

    // ---- merge kh partials via LDS scratch (stride 36 dwords: no 32-way conflict)
    float l_w = lacc[0];  // all rows identical (ones-A); complete over wave's 32-k window
    __builtin_amdgcn_s_barrier();
    float* scr = (float*)&smem[0][0][0];
    if (kh) {
        float* dst = scr + qh * 2304 + lane * 36;
#pragma unroll
        for (int dt = 0; dt < 2; ++dt)
#pragma unroll
            for (int G = 0; G < 4; ++G) {
                float4 st;
                st.x = ctx[dt][G * 4 + 0]; st.y = ctx[dt][G * 4 + 1];
                st.z = ctx[dt][G * 4 + 2]; st.w = ctx[dt][G * 4 + 3];
                *reinterpret_cast<float4*>(dst + dt * 16 + G * 4) = st;
            }
        scr[4608 + qh * 64 + lane] = l_w;
    }
    __builtin_amdgcn_s_barrier();
    if (!kh) {
        const float* src = scr + qh * 2304 + lane * 36;
        float l_full = l_w + scr[4608 + qh * 64 + lane];
        float inv_l = 1.0f / l_full;
        size_t ob0 = ((size_t)b * 2048 + qrow) * 1024 + h * 64 + 4 * hi;
#pragma unroll
        for (int dt = 0; dt < 2; ++dt)
#pragma unroll
            for (int G = 0; G < 4; ++G) {
                float4 pv = *reinterpret_cast<const float4*>(src + dt * 16 + G * 4);
                float4 st;
                st.x = (ctx[dt][G * 4 + 0] + pv.x) * inv_l;
                st.y = (ctx[dt][G * 4 + 1] + pv.y) * inv_l;
                st.z = (ctx[dt][G * 4 + 2] + pv.z) * inv_l;
                st.w = (ctx[dt][G * 4 + 3] + pv.w) * inv_l;
                *reinterpret_cast<float4*>(out + ob0 + dt * 32 + 8 * G) = st;
            }
    }
}

// ---------------------------------------------------------------- launch
extern "C" void kernel_launch(void* const* d_in, const int* in_sizes, int n_in,
                              void* d_out, int out_size, void* d_ws, size_t ws_size,
                              hipStream_t stream) {
    const float* X  = (const float*)d_in[0];
    const int* mask = (const int*)d_in[1];
    const float* Wq = (const float*)d_in[2];
    const float* bq = (const float*)d_in[3];
    const float* Wk = (const float*)d_in[4];
    const float* bk = (const float*)d_in[5];
    const float* Wv = (const float*)d_in[6];
    const float* bv = (const float*)d_in[7];
    float* out = (float*)d_out;

    char* ws = (char*)d_ws;
    const size_t SZ_X = (size_t)4096 * 1024 * 2;        // 8 MB f16 X
    const size_t SZ_W = (size_t)1024 * 1024 * 2;        // 2 MB per W plane
    const size_t SZ_Q = (size_t)2 * 16 * 2048 * 64 * 2; // 8 MB per QKV plane
    unsigned short* XF = (unsigned short*)(ws);
    unsigned short* WT = (unsigned short*)(ws + SZ_X);
    unsigned short* QF = (unsigned short*)(ws + SZ_X + 3 * SZ_W);
    unsigned short* KF = (unsigned short*)(ws + SZ_X + 3 * SZ_W + 1 * SZ_Q);
    unsigned short* VT = (unsigned short*)(ws + SZ_X + 3 * SZ_W + 2 * SZ_Q);

    prep_kernel<<<4864, 256, 0, stream>>>(X, Wq, Wk, Wv, XF, WT);
    qkv_gemm_kernel<<<dim3(32, 8, 3), 256, 0, stream>>>(XF, WT, bq, bk, bv, QF, KF, VT);
    attn_kernel<<<1024, 256, 0, stream>>>(QF, KF, VT, mask, out);
}